// Round 5
// baseline (3037.092 us; speedup 1.0000x reference)
//
#include <hip/hip_runtime.h>

#define BB 16
#define TT 12
#define NN 1024
#define EMB 10
#define DIN 21
#define DOUT 64
#define FF 85      // DIN + DOUT
#define FP 96      // padded feature stride (spmv output cols)
#define KFP 176    // padded 2*FF (=170) for per-node matmul K dim
#define BTN (BB * TT * NN)
#define ASCALE 256.0f
#define INV_ASCALE (1.0f / 256.0f)
#define LSCALE 4096.0f
#define INV_LSCALE (1.0f / 4096.0f)

typedef float4 f4;
typedef _Float16 f16;
typedef __attribute__((ext_vector_type(8))) _Float16 f16x8;
typedef __attribute__((ext_vector_type(4))) float f32x4;

// ---------------- cur hi/lo f16, transposed [b][t][f(21)][n] ----------------
__global__ __launch_bounds__(256) void k_embedT(const float* __restrict__ x,
    const float* __restrict__ Wtod, const float* __restrict__ btod,
    const float* __restrict__ Wdow, const float* __restrict__ bdow,
    f16* __restrict__ curh, f16* __restrict__ curl) {
  int idx = blockIdx.x * 256 + threadIdx.x;
  if (idx >= BB * TT * DIN * NN) return;
  int n = idx & 1023;
  int f = (idx >> 10) % DIN;
  int bt = idx / (DIN * 1024);
  const float* xp = x + ((size_t)bt * 1024 + n) * 3;
  float v;
  if (f == 0) v = xp[0];
  else if (f < 1 + EMB) {
    int tod = (int)xp[1];
    v = Wtod[tod * EMB + f - 1] + btod[f - 1];
  } else {
    int dow = (int)xp[2];
    v = Wdow[dow * EMB + f - 1 - EMB] + bdow[f - 1 - EMB];
  }
  f16 hi = (f16)v;
  curh[idx] = hi;
  curl[idx] = (f16)((v - (float)hi) * LSCALE);
}

// ---------------- pooled weights fp32, n-reuse: W[n][kf(176)][O] ----------------
// grid (KFP/KFB, NN/64), 256 thr; thread holds Wpool[d][kf][o4*4..] in regs, loops 64 n
__global__ __launch_bounds__(256) void k_pool(const float* __restrict__ E,
    const float* __restrict__ Wpool, float* __restrict__ W, int O) {
  int O4 = O >> 2;
  int o4 = threadIdx.x % O4;
  int kfi = threadIdx.x / O4;
  int KFB = 256 / O4;
  int kf = blockIdx.x * KFB + kfi;
  int n0 = blockIdx.y * 64;
  __shared__ float Es[64][EMB];
  for (int q = threadIdx.x; q < 64 * EMB / 4; q += 256)
    ((f4*)Es)[q] = ((const f4*)(E + n0 * EMB))[q];
  __syncthreads();
  f4 wp[EMB];
  bool valid = kf < 2 * FF;
#pragma unroll
  for (int d = 0; d < EMB; d++) {
    if (valid) wp[d] = *(const f4*)&Wpool[((size_t)d * 2 * FF + kf) * O + o4 * 4];
    else wp[d] = (f4){0.f, 0.f, 0.f, 0.f};
  }
  for (int ni = 0; ni < 64; ni++) {
    f4 a = (f4){0.f, 0.f, 0.f, 0.f};
#pragma unroll
    for (int d = 0; d < EMB; d++) {
      float e = Es[ni][d];
      a.x = fmaf(e, wp[d].x, a.x);
      a.y = fmaf(e, wp[d].y, a.y);
      a.z = fmaf(e, wp[d].z, a.z);
      a.w = fmaf(e, wp[d].w, a.w);
    }
    *(f4*)&W[((size_t)(n0 + ni) * KFP + kf) * O + o4 * 4] = a;
  }
}

__global__ __launch_bounds__(256) void k_poolb(const float* __restrict__ E,
    const float* __restrict__ bpool, float* __restrict__ bvec, int O) {
  int idx = blockIdx.x * 256 + threadIdx.x;
  if (idx >= NN * O) return;
  int o = idx % O, n = idx / O;
  float a = 0.f;
#pragma unroll
  for (int d = 0; d < EMB; d++) a += E[n * EMB + d] * bpool[d * O + o];
  bvec[idx] = a;
}

__global__ __launch_bounds__(256) void k_inith(const float* __restrict__ s,
    float* __restrict__ hb) {
  int i = blockIdx.x * 256 + threadIdx.x;
  if (i < BB * NN * DOUT) hb[i] = s[i];
}

// ---------------- W_QKV -> wbt[3][d][k] f16 + biasb[192] ----------------
__global__ __launch_bounds__(256) void k_cvtw(const float* __restrict__ WQ,
    const float* __restrict__ WK, const float* __restrict__ WV,
    const float* __restrict__ bQ, const float* __restrict__ bK, const float* __restrict__ bV,
    f16* __restrict__ wbt, float* __restrict__ biasb) {
  int idx = blockIdx.x * 256 + threadIdx.x;
  if (idx < 3 * DOUT * DOUT) {
    int mat = idx >> 12;
    int d = (idx >> 6) & 63;
    int k = idx & 63;
    const float* W = mat == 0 ? WQ : (mat == 1 ? WK : WV);
    wbt[idx] = (f16)(W[k * DOUT + d]);
  } else if (idx < 3 * DOUT * DOUT + 192) {
    int j = idx - 3 * DOUT * DOUT;
    const float* bb = (j >> 6) == 0 ? bQ : ((j >> 6) == 1 ? bK : bV);
    biasb[j] = bb[j & 63];
  }
}

// ---------------- fused MFMA spmv with on-the-fly A ----------------
// Y[b,i,f] = (1/256)*sum_j softmax_row(relu(c_i . E_j)) * X[b,j,f]
// sweep1: per-row online max/sum (VALU); sweep2: regenerate A fragments in regs,
// hi/lo split, 3-MFMA per (ks,nf). X rows: 0..20 cur hi/lo f16, 21..84 hsrc fp32 split.
__global__ __launch_bounds__(256) void k_spmv(
    const float* __restrict__ E, const float* __restrict__ ne1, const float* __restrict__ ne2,
    const f16* __restrict__ curh, const f16* __restrict__ curl, int t,
    const float* __restrict__ hsrc, float* __restrict__ Y) {
  int b = blockIdx.y;
  int i0 = blockIdx.x * 64;
  int tid = threadIdx.x;
  int lane = tid & 63, w = tid >> 6;
  int quad = lane >> 4, m = lane & 15;
  int irow = i0 + w * 16 + m;
  __shared__ __align__(16) float Ej[64][EMB];
  __shared__ __align__(16) f16 Xh[96][72];
  __shared__ __align__(16) f16 Xl[96][72];
  // pad rows 85..95 zero (visible after first barrier)
  for (int q = tid; q < 11 * 72; q += 256) {
    int f = 85 + q / 72, j = q % 72;
    Xh[f][j] = (f16)0.f;
    Xl[f][j] = (f16)0.f;
  }
  // per-lane row coefficients c[d] = E[irow][d] * g[d]
  float c[EMB];
#pragma unroll
  for (int d = 0; d < EMB; d++) {
    float g = ne1[(b * TT + t) * EMB + d] * ne2[(b * TT + t) * EMB + d];
    c[d] = E[irow * EMB + d] * g;
  }
  // ---- sweep 1: row stats ----
  float mx = 0.f, sm = 0.f;
  for (int j0 = 0; j0 < NN; j0 += 64) {
    __syncthreads();
    if (tid < 160) ((f4*)Ej)[tid] = ((const f4*)(E + j0 * EMB))[tid];
    __syncthreads();
    float sv[16];
#pragma unroll
    for (int ks = 0; ks < 2; ks++) {
#pragma unroll
      for (int jj = 0; jj < 8; jj++) {
        int j = ks * 32 + quad * 8 + jj;
        float s = 0.f;
#pragma unroll
        for (int d = 0; d < EMB; d++) s = fmaf(c[d], Ej[j][d], s);
        sv[ks * 8 + jj] = fmaxf(s, 0.f);
      }
    }
    float tm = sv[0];
#pragma unroll
    for (int k = 1; k < 16; k++) tm = fmaxf(tm, sv[k]);
    float nm = fmaxf(mx, tm);
    float ts = 0.f;
#pragma unroll
    for (int k = 0; k < 16; k++) ts += __expf(sv[k] - nm);
    sm = sm * __expf(mx - nm) + ts;
    mx = nm;
  }
  // combine the 4 quads (same row) via butterfly
#pragma unroll
  for (int off = 16; off <= 32; off <<= 1) {
    float omx = __shfl_xor(mx, off);
    float osm = __shfl_xor(sm, off);
    float nm = fmaxf(mx, omx);
    sm = sm * __expf(mx - nm) + osm * __expf(omx - nm);
    mx = nm;
  }
  float inv = ASCALE / sm;
  // ---- sweep 2: MFMA ----
  f32x4 accH[6], accL[6];
#pragma unroll
  for (int q = 0; q < 6; q++) {
    accH[q] = (f32x4){0.f, 0.f, 0.f, 0.f};
    accL[q] = (f32x4){0.f, 0.f, 0.f, 0.f};
  }
  const f16* curhb = curh + ((size_t)(b * TT + t) * DIN) * NN;
  const f16* curlb = curl + ((size_t)(b * TT + t) * DIN) * NN;
  const float* hbb = hsrc + (((size_t)b) << 16);
  for (int j0 = 0; j0 < NN; j0 += 64) {
    __syncthreads();
    if (tid < 160) ((f4*)Ej)[tid] = ((const f4*)(E + j0 * EMB))[tid];
    if (tid < 168) {
      int f = tid >> 3, cc = tid & 7;
      *(int4*)&Xh[f][cc * 8] = *(const int4*)&curhb[((size_t)f << 10) + j0 + cc * 8];
      *(int4*)&Xl[f][cc * 8] = *(const int4*)&curlb[((size_t)f << 10) + j0 + cc * 8];
    }
#pragma unroll
    for (int p = 0; p < 4; p++) {
      int q = p * 256 + tid;
      int jj = q >> 4, cc = q & 15;
      float hv4[4];
      *(f4*)hv4 = *(const f4*)&hbb[(((size_t)(j0 + jj)) << 6) + cc * 4];
#pragma unroll
      for (int k = 0; k < 4; k++) {
        float v = hv4[k];
        f16 hi = (f16)v;
        Xh[21 + cc * 4 + k][jj] = hi;
        Xl[21 + cc * 4 + k][jj] = (f16)((v - (float)hi) * LSCALE);
      }
    }
    __syncthreads();
#pragma unroll
    for (int ks = 0; ks < 2; ks++) {
      int k0 = ks * 32 + quad * 8;
      f16x8 a_h, a_l;
#pragma unroll
      for (int jj = 0; jj < 8; jj++) {
        int j = k0 + jj;
        float s = 0.f;
#pragma unroll
        for (int d = 0; d < EMB; d++) s = fmaf(c[d], Ej[j][d], s);
        s = fmaxf(s, 0.f);
        float a = __expf(s - mx) * inv;
        f16 hi = (f16)a;
        a_h[jj] = hi;
        a_l[jj] = (f16)((a - (float)hi) * LSCALE);
      }
#pragma unroll
      for (int nf = 0; nf < 6; nf++) {
        f16x8 x_h = *(const f16x8*)&Xh[nf * 16 + m][k0];
        f16x8 x_l = *(const f16x8*)&Xl[nf * 16 + m][k0];
        accH[nf] = __builtin_amdgcn_mfma_f32_16x16x32_f16(a_h, x_h, accH[nf], 0, 0, 0);
        accL[nf] = __builtin_amdgcn_mfma_f32_16x16x32_f16(a_h, x_l, accL[nf], 0, 0, 0);
        accL[nf] = __builtin_amdgcn_mfma_f32_16x16x32_f16(a_l, x_h, accL[nf], 0, 0, 0);
      }
    }
  }
  // C layout: col=lane&15, row=quad*4+reg
#pragma unroll
  for (int nf = 0; nf < 6; nf++) {
#pragma unroll
    for (int reg = 0; reg < 4; reg++) {
      int row = i0 + w * 16 + quad * 4 + reg;
      Y[((size_t)(b * NN) + row) * FP + nf * 16 + m] =
          (accH[nf][reg] + accL[nf][reg] * INV_LSCALE) * INV_ASCALE;
    }
  }
}

// ---------------- per-node gate matmul (fp32 W read once), k-split x2 ----------------
__global__ __launch_bounds__(256) void k_nodemm_g(
    const f16* __restrict__ curh, const f16* __restrict__ curl, int t,
    const float* __restrict__ hb, const float* __restrict__ T1,
    const float* __restrict__ Wg, const float* __restrict__ bg,
    float* __restrict__ r, float* __restrict__ zhb) {
  int n = blockIdx.x;
  int o = threadIdx.x & 127;
  int kh = threadIdx.x >> 7;
  __shared__ float X[BB][KFP];
  __shared__ float part[128][17];
  for (int q = threadIdx.x; q < BB * KFP; q += 256) {
    int bi = q / KFP, kf = q % KFP;
    float v = 0.f;
    if (kf < DIN) {
      size_t ci = (((size_t)(bi * TT + t) * DIN) + kf) * NN + n;
      v = (float)curh[ci] + (float)curl[ci] * INV_LSCALE;
    } else if (kf < FF) v = hb[(((size_t)bi << 10) + n) * DOUT + kf - DIN];
    else if (kf < 2 * FF) v = T1[(((size_t)bi << 10) + n) * FP + kf - FF];
    X[bi][kf] = v;
  }
  __syncthreads();
  float acc[BB];
#pragma unroll
  for (int bi = 0; bi < BB; bi++) acc[bi] = 0.f;
  const float* Wn = Wg + (size_t)n * KFP * 128 + o;
  for (int kf0 = kh * 88; kf0 < kh * 88 + 88; kf0 += 4) {
    float w0 = Wn[(size_t)(kf0 + 0) * 128];
    float w1 = Wn[(size_t)(kf0 + 1) * 128];
    float w2 = Wn[(size_t)(kf0 + 2) * 128];
    float w3 = Wn[(size_t)(kf0 + 3) * 128];
#pragma unroll
    for (int bi = 0; bi < BB; bi++) {
      f4 xv = *(f4*)&X[bi][kf0];
      acc[bi] = fmaf(xv.x, w0, fmaf(xv.y, w1, fmaf(xv.z, w2, fmaf(xv.w, w3, acc[bi]))));
    }
  }
  if (kh == 1) {
#pragma unroll
    for (int bi = 0; bi < BB; bi++) part[o][bi] = acc[bi];
  }
  __syncthreads();
  if (kh == 0) {
    float bias = bg[n * 128 + o];
#pragma unroll
    for (int bi = 0; bi < BB; bi++) {
      float v = acc[bi] + part[o][bi] + bias;
      v = 1.f / (1.f + __expf(-v));
      size_t off = (((size_t)bi << 10) + n) * DOUT;
      if (o < DOUT) zhb[off + o] = v * hb[off + o];
      else r[off + o - DOUT] = v;
    }
  }
}

// ---------------- per-node cand matmul + GRU (fp32 W read once), k-split x4 ----------------
__global__ __launch_bounds__(256) void k_nodemm_c(
    const f16* __restrict__ curh, const f16* __restrict__ curl, int t,
    const float* __restrict__ hb_in, const float* __restrict__ zhb, const float* __restrict__ T1,
    const float* __restrict__ Wc, const float* __restrict__ bc,
    const float* __restrict__ r, float* __restrict__ hb, f16* __restrict__ seqb) {
  int n = blockIdx.x;
  int o = threadIdx.x & 63;
  int kq = threadIdx.x >> 6;
  __shared__ float X[BB][KFP];
  __shared__ float part[3][64][17];
  for (int q = threadIdx.x; q < BB * KFP; q += 256) {
    int bi = q / KFP, kf = q % KFP;
    float v = 0.f;
    if (kf < DIN) {
      size_t ci = (((size_t)(bi * TT + t) * DIN) + kf) * NN + n;
      v = (float)curh[ci] + (float)curl[ci] * INV_LSCALE;
    } else if (kf < FF) v = zhb[(((size_t)bi << 10) + n) * DOUT + kf - DIN];
    else if (kf < 2 * FF) v = T1[(((size_t)bi << 10) + n) * FP + kf - FF];
    X[bi][kf] = v;
  }
  __syncthreads();
  float acc[BB];
#pragma unroll
  for (int bi = 0; bi < BB; bi++) acc[bi] = 0.f;
  const float* Wn = Wc + (size_t)n * KFP * 64 + o;
  for (int kf0 = kq * 44; kf0 < kq * 44 + 44; kf0 += 4) {
    float w0 = Wn[(size_t)(kf0 + 0) * 64];
    float w1 = Wn[(size_t)(kf0 + 1) * 64];
    float w2 = Wn[(size_t)(kf0 + 2) * 64];
    float w3 = Wn[(size_t)(kf0 + 3) * 64];
#pragma unroll
    for (int bi = 0; bi < BB; bi++) {
      f4 xv = *(f4*)&X[bi][kf0];
      acc[bi] = fmaf(xv.x, w0, fmaf(xv.y, w1, fmaf(xv.z, w2, fmaf(xv.w, w3, acc[bi]))));
    }
  }
  if (kq > 0) {
#pragma unroll
    for (int bi = 0; bi < BB; bi++) part[kq - 1][o][bi] = acc[bi];
  }
  __syncthreads();
  if (kq == 0) {
    float bias = bc[n * 64 + o];
#pragma unroll
    for (int bi = 0; bi < BB; bi++) {
      float v = acc[bi] + part[0][o][bi] + part[1][o][bi] + part[2][o][bi] + bias;
      float hc = tanhf(v);
      size_t off = (((size_t)bi << 10) + n) * DOUT + o;
      float rv = r[off];
      float hn = rv * hb_in[off] + (1.f - rv) * hc;
      hb[off] = hn;
      seqb[((size_t)(bi * TT + t) * NN + n) * DOUT + o] = (f16)hn;
    }
  }
}

// ---------------- QKV projection via MFMA: [196608 x 64] @ [64 x 192] ----------------
__global__ __launch_bounds__(256) void k_qkv(const f16* __restrict__ seqb,
    const f16* __restrict__ wbt, const float* __restrict__ biasb,
    f16* __restrict__ qkvb) {
  int R0 = blockIdx.x * 128;
  int tid = threadIdx.x;
  int lane = tid & 63, w = tid >> 6;
  int quad = lane >> 4, m = lane & 15;
  __shared__ __align__(16) f16 Sb[128][72];
  __shared__ __align__(16) f16 Wt[192][72];
#pragma unroll
  for (int p = 0; p < 4; p++) {
    int q = p * 256 + tid;
    int rr = q >> 3, cc = q & 7;
    *(int4*)&Sb[rr][cc * 8] = *(const int4*)&seqb[((size_t)(R0 + rr) << 6) + cc * 8];
  }
#pragma unroll
  for (int p = 0; p < 6; p++) {
    int q = p * 256 + tid;
    int rr = q >> 3, cc = q & 7;
    *(int4*)&Wt[rr][cc * 8] = *(const int4*)&wbt[((size_t)rr << 6) + cc * 8];
  }
  __syncthreads();
  f32x4 acc[2][12];
#pragma unroll
  for (int mi = 0; mi < 2; mi++)
#pragma unroll
    for (int nf = 0; nf < 12; nf++) acc[mi][nf] = (f32x4){0.f, 0.f, 0.f, 0.f};
#pragma unroll
  for (int ks = 0; ks < 2; ks++) {
    int k0 = ks * 32 + quad * 8;
    f16x8 a0 = *(const f16x8*)&Sb[w * 32 + m][k0];
    f16x8 a1 = *(const f16x8*)&Sb[w * 32 + 16 + m][k0];
#pragma unroll
    for (int nf = 0; nf < 12; nf++) {
      f16x8 bb = *(const f16x8*)&Wt[nf * 16 + m][k0];
      acc[0][nf] = __builtin_amdgcn_mfma_f32_16x16x32_f16(a0, bb, acc[0][nf], 0, 0, 0);
      acc[1][nf] = __builtin_amdgcn_mfma_f32_16x16x32_f16(a1, bb, acc[1][nf], 0, 0, 0);
    }
  }
  float bias_r[12];
#pragma unroll
  for (int nf = 0; nf < 12; nf++) bias_r[nf] = biasb[nf * 16 + m];
#pragma unroll
  for (int mi = 0; mi < 2; mi++) {
#pragma unroll
    for (int nf = 0; nf < 12; nf++) {
      int mat = nf >> 2;
      int d = (nf & 3) * 16 + m;
#pragma unroll
      for (int reg = 0; reg < 4; reg++) {
        int R = R0 + w * 32 + mi * 16 + quad * 4 + reg;
        qkvb[(size_t)mat * BTN * DOUT + ((size_t)R << 6) + d] = (f16)(acc[mi][nf][reg] + bias_r[nf]);
      }
    }
  }
}

// ---------------- temporal attention per (b,n) ----------------
__global__ __launch_bounds__(64) void k_attn2(const f16* __restrict__ qkvb,
    float* __restrict__ out) {
  int n = blockIdx.x, b = blockIdx.y;
  int d = threadIdx.x;
  const f16* Qb = qkvb;
  const f16* Kb = qkvb + (size_t)BTN * DOUT;
  const f16* Vb = qkvb + (size_t)2 * BTN * DOUT;
  __shared__ float Qs[TT][65], Ks[TT][65], at[TT][13];
  float vr[TT];
#pragma unroll
  for (int t = 0; t < TT; t++) {
    size_t off = ((size_t)(b * TT + t) * NN + n) * DOUT + d;
    Qs[t][d] = (float)Qb[off];
    Ks[t][d] = (float)Kb[off];
    vr[t] = (float)Vb[off];
  }
  __syncthreads();
  for (int idx = d; idx < TT * TT; idx += 64) {
    int tt = idx / TT, ss = idx % TT;
    float sc = 0.f;
#pragma unroll
    for (int k = 0; k < DOUT; k++) sc = fmaf(Qs[tt][k], Ks[ss][k], sc);
    at[tt][ss] = sc * 0.125f;
  }
  __syncthreads();
  if (d < TT) {
    float mx = -1e30f;
#pragma unroll
    for (int s = 0; s < TT; s++) mx = fmaxf(mx, at[d][s]);
    float sum = 0.f;
#pragma unroll
    for (int s = 0; s < TT; s++) { float e = __expf(at[d][s] - mx); at[d][s] = e; sum += e; }
    float inv = 1.f / sum;
#pragma unroll
    for (int s = 0; s < TT; s++) at[d][s] *= inv;
  }
  __syncthreads();
  float o[TT];
#pragma unroll
  for (int t = 0; t < TT; t++) o[t] = 0.f;
#pragma unroll
  for (int s = 0; s < TT; s++) {
    float vv = vr[s];
#pragma unroll
    for (int t = 0; t < TT; t++) o[t] = fmaf(at[t][s], vv, o[t]);
  }
#pragma unroll
  for (int t = 0; t < TT; t++)
    out[((size_t)(b * TT + t) * NN + n) * DOUT + d] = o[t];
}

__global__ __launch_bounds__(256) void k_hlast(const float* __restrict__ h, float* __restrict__ o) {
  int i = blockIdx.x * 256 + threadIdx.x;
  if (i < BB * NN * DOUT) o[i] = h[i];
}

extern "C" void kernel_launch(void* const* d_in, const int* in_sizes, int n_in,
                              void* d_out, int out_size, void* d_ws, size_t ws_size,
                              hipStream_t stream) {
  const float* x        = (const float*)d_in[0];
  const float* init_st  = (const float*)d_in[1];
  const float* ne_tod   = (const float*)d_in[2];
  const float* ne_dow   = (const float*)d_in[3];
  const float* E        = (const float*)d_in[4];
  const float* Wtod     = (const float*)d_in[5];
  const float* btod     = (const float*)d_in[6];
  const float* Wdow     = (const float*)d_in[7];
  const float* bdow     = (const float*)d_in[8];
  const float* WQ       = (const float*)d_in[9];
  const float* bQ       = (const float*)d_in[10];
  const float* WK       = (const float*)d_in[11];
  const float* bK       = (const float*)d_in[12];
  const float* WV       = (const float*)d_in[13];
  const float* bV       = (const float*)d_in[14];
  const float* Wpool_g  = (const float*)d_in[15];
  const float* bpool_g  = (const float*)d_in[16];
  const float* Wpool_c  = (const float*)d_in[17];
  const float* bpool_c  = (const float*)d_in[18];

  float* out = (float*)d_out;
  float* hlast_out = out + (size_t)BTN * DOUT;
  // park f16 seq history in the (not-yet-written) front of d_out: 25.2 MB < 50.3 MB
  f16* seqb = (f16*)d_out;

  char* P = (char*)d_ws;
  auto alloc = [&](size_t bytes) { char* r = P; P += (bytes + 255) & ~(size_t)255; return r; };
  f16* curh  = (f16*)alloc((size_t)BB * TT * DIN * NN * 2);   // 8.26 MB
  f16* curl  = (f16*)alloc((size_t)BB * TT * DIN * NN * 2);   // 8.26 MB
  float* Wg  = (float*)alloc((size_t)NN * KFP * 128 * 4);     // 92.3 MB
  float* Wc  = (float*)alloc((size_t)NN * KFP * 64 * 4);      // 46.1 MB
  float* bg  = (float*)alloc((size_t)NN * 128 * 4);
  float* bc  = (float*)alloc((size_t)NN * 64 * 4);
  float* hb  = (float*)alloc((size_t)BB * NN * DOUT * 4);     // 4.2 MB
  f16* wbt   = (f16*)alloc((size_t)3 * DOUT * DOUT * 2);
  float* biasb = (float*)alloc(192 * 4);
  float* T1  = (float*)alloc((size_t)BB * NN * FP * 4);       // 6.3 MB
  float* rb  = (float*)alloc((size_t)BB * NN * DOUT * 4);     // 4.2 MB
  float* zhb = (float*)alloc((size_t)BB * NN * DOUT * 4);     // 4.2 MB
  f16* qkvb  = (f16*)alloc((size_t)3 * BTN * DOUT * 2);       // 75.5 MB
  // total ws ~250 MB (< 260.6 MB proven in round 1)

  k_embedT<<<(BB * TT * DIN * NN + 255) / 256, 256, 0, stream>>>(x, Wtod, btod, Wdow, bdow, curh, curl);
  k_pool<<<dim3(KFP / 8, NN / 64), 256, 0, stream>>>(E, Wpool_g, Wg, 128);
  k_pool<<<dim3(KFP / 16, NN / 64), 256, 0, stream>>>(E, Wpool_c, Wc, 64);
  k_poolb<<<(NN * 128 + 255) / 256, 256, 0, stream>>>(E, bpool_g, bg, 128);
  k_poolb<<<(NN * 64 + 255) / 256, 256, 0, stream>>>(E, bpool_c, bc, 64);
  k_inith<<<(BB * NN * DOUT + 255) / 256, 256, 0, stream>>>(init_st, hb);
  k_cvtw<<<(3 * DOUT * DOUT + 192 + 255) / 256, 256, 0, stream>>>(WQ, WK, WV, bQ, bK, bV, wbt, biasb);

  for (int t = 0; t < TT; t++) {
    k_spmv<<<dim3(NN / 64, BB), 256, 0, stream>>>(E, ne_tod, ne_dow, curh, curl, t, hb, T1);
    k_nodemm_g<<<NN, 256, 0, stream>>>(curh, curl, t, hb, T1, Wg, bg, rb, zhb);
    k_spmv<<<dim3(NN / 64, BB), 256, 0, stream>>>(E, ne_tod, ne_dow, curh, curl, t, zhb, T1);
    k_nodemm_c<<<NN, 256, 0, stream>>>(curh, curl, t, hb, zhb, T1, Wc, bc, rb, hb, seqb);
  }

  k_qkv<<<BTN / 128, 256, 0, stream>>>(seqb, wbt, biasb, qkvb);
  k_attn2<<<dim3(NN, BB), 64, 0, stream>>>(qkvb, out);
  k_hlast<<<(BB * NN * DOUT + 255) / 256, 256, 0, stream>>>(hb, hlast_out);
}

// Round 6
// 2394.383 us; speedup vs baseline: 1.2684x; 1.2684x over previous
//
#include <hip/hip_runtime.h>

#define BB 16
#define TT 12
#define NN 1024
#define EMB 10
#define DIN 21
#define DOUT 64
#define FF 85      // DIN + DOUT
#define FP 96      // padded feature stride (gate spmv output cols)
#define KFP 176    // padded 2*FF (=170) for per-node matmul K dim
#define BTN (BB * TT * NN)
#define ASCALE 256.0f
#define INV_ASCALE (1.0f / 256.0f)
#define LSCALE 4096.0f
#define INV_LSCALE (1.0f / 4096.0f)

typedef float4 f4;
typedef _Float16 f16;
typedef __attribute__((ext_vector_type(8))) _Float16 f16x8;
typedef __attribute__((ext_vector_type(4))) float f32x4;

// ---------------- cur hi/lo f16, transposed [b][t][f(21)][n] ----------------
__global__ __launch_bounds__(256) void k_embedT(const float* __restrict__ x,
    const float* __restrict__ Wtod, const float* __restrict__ btod,
    const float* __restrict__ Wdow, const float* __restrict__ bdow,
    f16* __restrict__ curh, f16* __restrict__ curl) {
  int idx = blockIdx.x * 256 + threadIdx.x;
  if (idx >= BB * TT * DIN * NN) return;
  int n = idx & 1023;
  int f = (idx >> 10) % DIN;
  int bt = idx / (DIN * 1024);
  const float* xp = x + ((size_t)bt * 1024 + n) * 3;
  float v;
  if (f == 0) v = xp[0];
  else if (f < 1 + EMB) {
    int tod = (int)xp[1];
    v = Wtod[tod * EMB + f - 1] + btod[f - 1];
  } else {
    int dow = (int)xp[2];
    v = Wdow[dow * EMB + f - 1 - EMB] + bdow[f - 1 - EMB];
  }
  f16 hi = (f16)v;
  curh[idx] = hi;
  curl[idx] = (f16)((v - (float)hi) * LSCALE);
}

// ---------------- pooled weights fp32, n-reuse: W[n][kf(176)][O] ----------------
__global__ __launch_bounds__(256) void k_pool(const float* __restrict__ E,
    const float* __restrict__ Wpool, float* __restrict__ W, int O) {
  int O4 = O >> 2;
  int o4 = threadIdx.x % O4;
  int kfi = threadIdx.x / O4;
  int KFB = 256 / O4;
  int kf = blockIdx.x * KFB + kfi;
  int n0 = blockIdx.y * 64;
  __shared__ float Es[64][EMB];
  for (int q = threadIdx.x; q < 64 * EMB / 4; q += 256)
    ((f4*)Es)[q] = ((const f4*)(E + n0 * EMB))[q];
  __syncthreads();
  f4 wp[EMB];
  bool valid = kf < 2 * FF;
#pragma unroll
  for (int d = 0; d < EMB; d++) {
    if (valid) wp[d] = *(const f4*)&Wpool[((size_t)d * 2 * FF + kf) * O + o4 * 4];
    else wp[d] = (f4){0.f, 0.f, 0.f, 0.f};
  }
  for (int ni = 0; ni < 64; ni++) {
    f4 a = (f4){0.f, 0.f, 0.f, 0.f};
#pragma unroll
    for (int d = 0; d < EMB; d++) {
      float e = Es[ni][d];
      a.x = fmaf(e, wp[d].x, a.x);
      a.y = fmaf(e, wp[d].y, a.y);
      a.z = fmaf(e, wp[d].z, a.z);
      a.w = fmaf(e, wp[d].w, a.w);
    }
    *(f4*)&W[((size_t)(n0 + ni) * KFP + kf) * O + o4 * 4] = a;
  }
}

__global__ __launch_bounds__(256) void k_poolb(const float* __restrict__ E,
    const float* __restrict__ bpool, float* __restrict__ bvec, int O) {
  int idx = blockIdx.x * 256 + threadIdx.x;
  if (idx >= NN * O) return;
  int o = idx % O, n = idx / O;
  float a = 0.f;
#pragma unroll
  for (int d = 0; d < EMB; d++) a += E[n * EMB + d] * bpool[d * O + o];
  bvec[idx] = a;
}

__global__ __launch_bounds__(256) void k_inith(const float* __restrict__ s,
    float* __restrict__ hb) {
  int i = blockIdx.x * 256 + threadIdx.x;
  if (i < BB * NN * DOUT) hb[i] = s[i];
}

// ---------------- W_QKV -> wbt[3][d][k] f16 + biasb[192] ----------------
__global__ __launch_bounds__(256) void k_cvtw(const float* __restrict__ WQ,
    const float* __restrict__ WK, const float* __restrict__ WV,
    const float* __restrict__ bQ, const float* __restrict__ bK, const float* __restrict__ bV,
    f16* __restrict__ wbt, float* __restrict__ biasb) {
  int idx = blockIdx.x * 256 + threadIdx.x;
  if (idx < 3 * DOUT * DOUT) {
    int mat = idx >> 12;
    int d = (idx >> 6) & 63;
    int k = idx & 63;
    const float* W = mat == 0 ? WQ : (mat == 1 ? WK : WV);
    wbt[idx] = (f16)(W[k * DOUT + d]);
  } else if (idx < 3 * DOUT * DOUT + 192) {
    int j = idx - 3 * DOUT * DOUT;
    const float* bb = (j >> 6) == 0 ? bQ : ((j >> 6) == 1 ? bK : bV);
    biasb[j] = bb[j & 63];
  }
}

// ---------------- A = softmax(relu(scores))*256 -> Ah + Al' (lo x4096), f16 ----------------
__global__ __launch_bounds__(256) void k_scores(const float* __restrict__ E,
    const float* __restrict__ ne1, const float* __restrict__ ne2, int t,
    f16* __restrict__ Ah, f16* __restrict__ Al) {
  int b = blockIdx.y;
  int i0 = blockIdx.x * 4;
  int tid = threadIdx.x;
  int lane = tid & 63;
  int wid = tid >> 6;
  __shared__ float redm[4][4];
  __shared__ float reds[4][4];
  float g[EMB];
#pragma unroll
  for (int d = 0; d < EMB; d++)
    g[d] = ne1[(b * TT + t) * EMB + d] * ne2[(b * TT + t) * EMB + d];
  float c[4][EMB];
#pragma unroll
  for (int ii = 0; ii < 4; ii++)
#pragma unroll
    for (int d = 0; d < EMB; d++)
      c[ii][d] = E[(i0 + ii) * EMB + d] * g[d];
  float s[4][4];
#pragma unroll
  for (int jj = 0; jj < 4; jj++) {
    int j = jj * 256 + tid;
    float Ej[EMB];
#pragma unroll
    for (int d = 0; d < EMB; d++) Ej[d] = E[j * EMB + d];
#pragma unroll
    for (int ii = 0; ii < 4; ii++) {
      float acc = 0.f;
#pragma unroll
      for (int d = 0; d < EMB; d++) acc = fmaf(c[ii][d], Ej[d], acc);
      s[ii][jj] = fmaxf(acc, 0.f);
    }
  }
  float m4[4];
#pragma unroll
  for (int ii = 0; ii < 4; ii++) {
    float v = fmaxf(fmaxf(s[ii][0], s[ii][1]), fmaxf(s[ii][2], s[ii][3]));
#pragma unroll
    for (int off = 32; off > 0; off >>= 1) v = fmaxf(v, __shfl_xor(v, off));
    if (lane == 0) redm[wid][ii] = v;
  }
  __syncthreads();
#pragma unroll
  for (int ii = 0; ii < 4; ii++)
    m4[ii] = fmaxf(fmaxf(redm[0][ii], redm[1][ii]), fmaxf(redm[2][ii], redm[3][ii]));
  float e[4][4];
  float inv[4];
#pragma unroll
  for (int ii = 0; ii < 4; ii++) {
    float lsum = 0.f;
#pragma unroll
    for (int jj = 0; jj < 4; jj++) { e[ii][jj] = __expf(s[ii][jj] - m4[ii]); lsum += e[ii][jj]; }
#pragma unroll
    for (int off = 32; off > 0; off >>= 1) lsum += __shfl_xor(lsum, off);
    if (lane == 0) reds[wid][ii] = lsum;
  }
  __syncthreads();
#pragma unroll
  for (int ii = 0; ii < 4; ii++)
    inv[ii] = ASCALE / (reds[0][ii] + reds[1][ii] + reds[2][ii] + reds[3][ii]);
#pragma unroll
  for (int ii = 0; ii < 4; ii++) {
    size_t base = ((size_t)(b * NN) + i0 + ii) * NN;
#pragma unroll
    for (int jj = 0; jj < 4; jj++) {
      float a = e[ii][jj] * inv[ii];
      f16 hi = (f16)a;
      Ah[base + jj * 256 + tid] = hi;
      Al[base + jj * 256 + tid] = (f16)((a - (float)hi) * LSCALE);
    }
  }
}

// ---------------- gate spmv: 32-row tile x 96 cols, hi/lo MFMA ----------------
// waves: rg=w&1 (16-row group), cg=w>>1 (nf 0-2 / 3-5)
__global__ __launch_bounds__(256) void k_spmv_g(
    const f16* __restrict__ Ah, const f16* __restrict__ Al,
    const f16* __restrict__ curh, const f16* __restrict__ curl, int t,
    const float* __restrict__ hsrc, float* __restrict__ Y) {
  int b = blockIdx.y;
  int i0 = blockIdx.x * 32;
  int tid = threadIdx.x;
  int lane = tid & 63, w = tid >> 6;
  int rg = w & 1, cg = w >> 1;
  int quad = lane >> 4, m = lane & 15;
  __shared__ __align__(16) f16 As_h[32][72];
  __shared__ __align__(16) f16 As_l[32][72];
  __shared__ __align__(16) f16 Xh[96][72];
  __shared__ __align__(16) f16 Xl[96][72];
  for (int q = tid; q < 11 * 72; q += 256) {
    int f = 85 + q / 72, j = q % 72;
    Xh[f][j] = (f16)0.f;
    Xl[f][j] = (f16)0.f;
  }
  f32x4 accH[3], accL[3];
#pragma unroll
  for (int q = 0; q < 3; q++) {
    accH[q] = (f32x4){0.f, 0.f, 0.f, 0.f};
    accL[q] = (f32x4){0.f, 0.f, 0.f, 0.f};
  }
  const f16* Ahb = Ah + ((size_t)(b * NN + i0)) * NN;
  const f16* Alb = Al + ((size_t)(b * NN + i0)) * NN;
  const f16* curhb = curh + ((size_t)(b * TT + t) * DIN) * NN;
  const f16* curlb = curl + ((size_t)(b * TT + t) * DIN) * NN;
  const float* hbb = hsrc + (((size_t)b) << 16);
  for (int j0 = 0; j0 < NN; j0 += 64) {
    {
      int r = tid >> 3, cc = tid & 7;  // 32 rows x 8 chunks
      *(int4*)&As_h[r][cc * 8] = *(const int4*)&Ahb[(size_t)r * NN + j0 + cc * 8];
      *(int4*)&As_l[r][cc * 8] = *(const int4*)&Alb[(size_t)r * NN + j0 + cc * 8];
    }
    if (tid < 168) {
      int f = tid >> 3, cc = tid & 7;
      *(int4*)&Xh[f][cc * 8] = *(const int4*)&curhb[((size_t)f << 10) + j0 + cc * 8];
      *(int4*)&Xl[f][cc * 8] = *(const int4*)&curlb[((size_t)f << 10) + j0 + cc * 8];
    }
#pragma unroll
    for (int p = 0; p < 4; p++) {
      int q = p * 256 + tid;
      int jj = q >> 4, cc = q & 15;
      float hv4[4];
      *(f4*)hv4 = *(const f4*)&hbb[(((size_t)(j0 + jj)) << 6) + cc * 4];
#pragma unroll
      for (int k = 0; k < 4; k++) {
        float v = hv4[k];
        f16 hi = (f16)v;
        Xh[21 + cc * 4 + k][jj] = hi;
        Xl[21 + cc * 4 + k][jj] = (f16)((v - (float)hi) * LSCALE);
      }
    }
    __syncthreads();
#pragma unroll
    for (int ks = 0; ks < 2; ks++) {
      int k0 = ks * 32 + quad * 8;
      f16x8 a_h = *(const f16x8*)&As_h[rg * 16 + m][k0];
      f16x8 a_l = *(const f16x8*)&As_l[rg * 16 + m][k0];
#pragma unroll
      for (int nfi = 0; nfi < 3; nfi++) {
        int nf = cg * 3 + nfi;
        f16x8 x_h = *(const f16x8*)&Xh[nf * 16 + m][k0];
        f16x8 x_l = *(const f16x8*)&Xl[nf * 16 + m][k0];
        accH[nfi] = __builtin_amdgcn_mfma_f32_16x16x32_f16(a_h, x_h, accH[nfi], 0, 0, 0);
        accL[nfi] = __builtin_amdgcn_mfma_f32_16x16x32_f16(a_h, x_l, accL[nfi], 0, 0, 0);
        accL[nfi] = __builtin_amdgcn_mfma_f32_16x16x32_f16(a_l, x_h, accL[nfi], 0, 0, 0);
      }
    }
    __syncthreads();
  }
#pragma unroll
  for (int nfi = 0; nfi < 3; nfi++) {
    int nf = cg * 3 + nfi;
#pragma unroll
    for (int reg = 0; reg < 4; reg++) {
      int row = i0 + rg * 16 + quad * 4 + reg;
      Y[((size_t)(b * NN) + row) * FP + nf * 16 + m] =
          (accH[nfi][reg] + accL[nfi][reg] * INV_LSCALE) * INV_ASCALE;
    }
  }
}

// ---------------- cand spmv: 32-row tile x 64 cols (A @ (z*h) only) ----------------
// waves: rg=w&1, cg=w>>1 (nf pair); output T1c[b][n][64]
__global__ __launch_bounds__(256) void k_spmv_c(
    const f16* __restrict__ Ah, const f16* __restrict__ Al,
    const float* __restrict__ hsrc, float* __restrict__ Y) {
  int b = blockIdx.y;
  int i0 = blockIdx.x * 32;
  int tid = threadIdx.x;
  int lane = tid & 63, w = tid >> 6;
  int rg = w & 1, cg = w >> 1;
  int quad = lane >> 4, m = lane & 15;
  __shared__ __align__(16) f16 As_h[32][72];
  __shared__ __align__(16) f16 As_l[32][72];
  __shared__ __align__(16) f16 Xh[64][72];
  __shared__ __align__(16) f16 Xl[64][72];
  f32x4 accH[2], accL[2];
#pragma unroll
  for (int q = 0; q < 2; q++) {
    accH[q] = (f32x4){0.f, 0.f, 0.f, 0.f};
    accL[q] = (f32x4){0.f, 0.f, 0.f, 0.f};
  }
  const f16* Ahb = Ah + ((size_t)(b * NN + i0)) * NN;
  const f16* Alb = Al + ((size_t)(b * NN + i0)) * NN;
  const float* hbb = hsrc + (((size_t)b) << 16);
  for (int j0 = 0; j0 < NN; j0 += 64) {
    {
      int r = tid >> 3, cc = tid & 7;
      *(int4*)&As_h[r][cc * 8] = *(const int4*)&Ahb[(size_t)r * NN + j0 + cc * 8];
      *(int4*)&As_l[r][cc * 8] = *(const int4*)&Alb[(size_t)r * NN + j0 + cc * 8];
    }
#pragma unroll
    for (int p = 0; p < 4; p++) {
      int q = p * 256 + tid;
      int jj = q >> 4, cc = q & 15;
      float hv4[4];
      *(f4*)hv4 = *(const f4*)&hbb[(((size_t)(j0 + jj)) << 6) + cc * 4];
#pragma unroll
      for (int k = 0; k < 4; k++) {
        float v = hv4[k];
        f16 hi = (f16)v;
        Xh[cc * 4 + k][jj] = hi;
        Xl[cc * 4 + k][jj] = (f16)((v - (float)hi) * LSCALE);
      }
    }
    __syncthreads();
#pragma unroll
    for (int ks = 0; ks < 2; ks++) {
      int k0 = ks * 32 + quad * 8;
      f16x8 a_h = *(const f16x8*)&As_h[rg * 16 + m][k0];
      f16x8 a_l = *(const f16x8*)&As_l[rg * 16 + m][k0];
#pragma unroll
      for (int nfi = 0; nfi < 2; nfi++) {
        int nf = cg * 2 + nfi;
        f16x8 x_h = *(const f16x8*)&Xh[nf * 16 + m][k0];
        f16x8 x_l = *(const f16x8*)&Xl[nf * 16 + m][k0];
        accH[nfi] = __builtin_amdgcn_mfma_f32_16x16x32_f16(a_h, x_h, accH[nfi], 0, 0, 0);
        accL[nfi] = __builtin_amdgcn_mfma_f32_16x16x32_f16(a_h, x_l, accL[nfi], 0, 0, 0);
        accL[nfi] = __builtin_amdgcn_mfma_f32_16x16x32_f16(a_l, x_h, accL[nfi], 0, 0, 0);
      }
    }
    __syncthreads();
  }
#pragma unroll
  for (int nfi = 0; nfi < 2; nfi++) {
    int nf = cg * 2 + nfi;
#pragma unroll
    for (int reg = 0; reg < 4; reg++) {
      int row = i0 + rg * 16 + quad * 4 + reg;
      Y[(((size_t)(b * NN) + row) << 6) + nf * 16 + m] =
          (accH[nfi][reg] + accL[nfi][reg] * INV_LSCALE) * INV_ASCALE;
    }
  }
}

// ---------------- per-node gate matmul (fp32 W read once), k-split x2 ----------------
__global__ __launch_bounds__(256) void k_nodemm_g(
    const f16* __restrict__ curh, const f16* __restrict__ curl, int t,
    const float* __restrict__ hb, const float* __restrict__ T1,
    const float* __restrict__ Wg, const float* __restrict__ bg,
    float* __restrict__ r, float* __restrict__ zhb) {
  int n = blockIdx.x;
  int o = threadIdx.x & 127;
  int kh = threadIdx.x >> 7;
  __shared__ float X[BB][KFP];
  __shared__ float part[128][17];
  for (int q = threadIdx.x; q < BB * KFP; q += 256) {
    int bi = q / KFP, kf = q % KFP;
    float v = 0.f;
    if (kf < DIN) {
      size_t ci = (((size_t)(bi * TT + t) * DIN) + kf) * NN + n;
      v = (float)curh[ci] + (float)curl[ci] * INV_LSCALE;
    } else if (kf < FF) v = hb[(((size_t)bi << 10) + n) * DOUT + kf - DIN];
    else if (kf < 2 * FF) v = T1[(((size_t)bi << 10) + n) * FP + kf - FF];
    X[bi][kf] = v;
  }
  __syncthreads();
  float acc[BB];
#pragma unroll
  for (int bi = 0; bi < BB; bi++) acc[bi] = 0.f;
  const float* Wn = Wg + (size_t)n * KFP * 128 + o;
  for (int kf0 = kh * 88; kf0 < kh * 88 + 88; kf0 += 4) {
    float w0 = Wn[(size_t)(kf0 + 0) * 128];
    float w1 = Wn[(size_t)(kf0 + 1) * 128];
    float w2 = Wn[(size_t)(kf0 + 2) * 128];
    float w3 = Wn[(size_t)(kf0 + 3) * 128];
#pragma unroll
    for (int bi = 0; bi < BB; bi++) {
      f4 xv = *(f4*)&X[bi][kf0];
      acc[bi] = fmaf(xv.x, w0, fmaf(xv.y, w1, fmaf(xv.z, w2, fmaf(xv.w, w3, acc[bi]))));
    }
  }
  if (kh == 1) {
#pragma unroll
    for (int bi = 0; bi < BB; bi++) part[o][bi] = acc[bi];
  }
  __syncthreads();
  if (kh == 0) {
    float bias = bg[n * 128 + o];
#pragma unroll
    for (int bi = 0; bi < BB; bi++) {
      float v = acc[bi] + part[o][bi] + bias;
      v = 1.f / (1.f + __expf(-v));
      size_t off = (((size_t)bi << 10) + n) * DOUT;
      if (o < DOUT) zhb[off + o] = v * hb[off + o];
      else r[off + o - DOUT] = v;
    }
  }
}

// ---------------- per-node cand matmul + GRU (fp32 W once), k-split x4 ----------------
// T1 cols 0..20 come from gate's T1g (A@cur), 21..84 from T1c (A@(z*h))
__global__ __launch_bounds__(256) void k_nodemm_c(
    const f16* __restrict__ curh, const f16* __restrict__ curl, int t,
    const float* __restrict__ hb_in, const float* __restrict__ zhb,
    const float* __restrict__ T1g, const float* __restrict__ T1c,
    const float* __restrict__ Wc, const float* __restrict__ bc,
    const float* __restrict__ r, float* __restrict__ hb, f16* __restrict__ seqb) {
  int n = blockIdx.x;
  int o = threadIdx.x & 63;
  int kq = threadIdx.x >> 6;
  __shared__ float X[BB][KFP];
  __shared__ float part[3][64][17];
  for (int q = threadIdx.x; q < BB * KFP; q += 256) {
    int bi = q / KFP, kf = q % KFP;
    float v = 0.f;
    if (kf < DIN) {
      size_t ci = (((size_t)(bi * TT + t) * DIN) + kf) * NN + n;
      v = (float)curh[ci] + (float)curl[ci] * INV_LSCALE;
    } else if (kf < FF) v = zhb[(((size_t)bi << 10) + n) * DOUT + kf - DIN];
    else if (kf < 2 * FF) {
      int u = kf - FF;
      v = (u < DIN) ? T1g[(((size_t)bi << 10) + n) * FP + u]
                    : T1c[((((size_t)bi << 10) + n) << 6) + (u - DIN)];
    }
    X[bi][kf] = v;
  }
  __syncthreads();
  float acc[BB];
#pragma unroll
  for (int bi = 0; bi < BB; bi++) acc[bi] = 0.f;
  const float* Wn = Wc + (size_t)n * KFP * 64 + o;
  for (int kf0 = kq * 44; kf0 < kq * 44 + 44; kf0 += 4) {
    float w0 = Wn[(size_t)(kf0 + 0) * 64];
    float w1 = Wn[(size_t)(kf0 + 1) * 64];
    float w2 = Wn[(size_t)(kf0 + 2) * 64];
    float w3 = Wn[(size_t)(kf0 + 3) * 64];
#pragma unroll
    for (int bi = 0; bi < BB; bi++) {
      f4 xv = *(f4*)&X[bi][kf0];
      acc[bi] = fmaf(xv.x, w0, fmaf(xv.y, w1, fmaf(xv.z, w2, fmaf(xv.w, w3, acc[bi]))));
    }
  }
  if (kq > 0) {
#pragma unroll
    for (int bi = 0; bi < BB; bi++) part[kq - 1][o][bi] = acc[bi];
  }
  __syncthreads();
  if (kq == 0) {
    float bias = bc[n * 64 + o];
#pragma unroll
    for (int bi = 0; bi < BB; bi++) {
      float v = acc[bi] + part[0][o][bi] + part[1][o][bi] + part[2][o][bi] + bias;
      float hc = tanhf(v);
      size_t off = (((size_t)bi << 10) + n) * DOUT + o;
      float rv = r[off];
      float hn = rv * hb_in[off] + (1.f - rv) * hc;
      hb[off] = hn;
      seqb[((size_t)(bi * TT + t) * NN + n) * DOUT + o] = (f16)hn;
    }
  }
}

// ---------------- QKV projection via MFMA: [196608 x 64] @ [64 x 192] ----------------
__global__ __launch_bounds__(256) void k_qkv(const f16* __restrict__ seqb,
    const f16* __restrict__ wbt, const float* __restrict__ biasb,
    f16* __restrict__ qkvb) {
  int R0 = blockIdx.x * 128;
  int tid = threadIdx.x;
  int lane = tid & 63, w = tid >> 6;
  int quad = lane >> 4, m = lane & 15;
  __shared__ __align__(16) f16 Sb[128][72];
  __shared__ __align__(16) f16 Wt[192][72];
#pragma unroll
  for (int p = 0; p < 4; p++) {
    int q = p * 256 + tid;
    int rr = q >> 3, cc = q & 7;
    *(int4*)&Sb[rr][cc * 8] = *(const int4*)&seqb[((size_t)(R0 + rr) << 6) + cc * 8];
  }
#pragma unroll
  for (int p = 0; p < 6; p++) {
    int q = p * 256 + tid;
    int rr = q >> 3, cc = q & 7;
    *(int4*)&Wt[rr][cc * 8] = *(const int4*)&wbt[((size_t)rr << 6) + cc * 8];
  }
  __syncthreads();
  f32x4 acc[2][12];
#pragma unroll
  for (int mi = 0; mi < 2; mi++)
#pragma unroll
    for (int nf = 0; nf < 12; nf++) acc[mi][nf] = (f32x4){0.f, 0.f, 0.f, 0.f};
#pragma unroll
  for (int ks = 0; ks < 2; ks++) {
    int k0 = ks * 32 + quad * 8;
    f16x8 a0 = *(const f16x8*)&Sb[w * 32 + m][k0];
    f16x8 a1 = *(const f16x8*)&Sb[w * 32 + 16 + m][k0];
#pragma unroll
    for (int nf = 0; nf < 12; nf++) {
      f16x8 bb = *(const f16x8*)&Wt[nf * 16 + m][k0];
      acc[0][nf] = __builtin_amdgcn_mfma_f32_16x16x32_f16(a0, bb, acc[0][nf], 0, 0, 0);
      acc[1][nf] = __builtin_amdgcn_mfma_f32_16x16x32_f16(a1, bb, acc[1][nf], 0, 0, 0);
    }
  }
  float bias_r[12];
#pragma unroll
  for (int nf = 0; nf < 12; nf++) bias_r[nf] = biasb[nf * 16 + m];
#pragma unroll
  for (int mi = 0; mi < 2; mi++) {
#pragma unroll
    for (int nf = 0; nf < 12; nf++) {
      int mat = nf >> 2;
      int d = (nf & 3) * 16 + m;
#pragma unroll
      for (int reg = 0; reg < 4; reg++) {
        int R = R0 + w * 32 + mi * 16 + quad * 4 + reg;
        qkvb[(size_t)mat * BTN * DOUT + ((size_t)R << 6) + d] = (f16)(acc[mi][nf][reg] + bias_r[nf]);
      }
    }
  }
}

// ---------------- temporal attention per (b,n) ----------------
__global__ __launch_bounds__(64) void k_attn2(const f16* __restrict__ qkvb,
    float* __restrict__ out) {
  int n = blockIdx.x, b = blockIdx.y;
  int d = threadIdx.x;
  const f16* Qb = qkvb;
  const f16* Kb = qkvb + (size_t)BTN * DOUT;
  const f16* Vb = qkvb + (size_t)2 * BTN * DOUT;
  __shared__ float Qs[TT][65], Ks[TT][65], at[TT][13];
  float vr[TT];
#pragma unroll
  for (int t = 0; t < TT; t++) {
    size_t off = ((size_t)(b * TT + t) * NN + n) * DOUT + d;
    Qs[t][d] = (float)Qb[off];
    Ks[t][d] = (float)Kb[off];
    vr[t] = (float)Vb[off];
  }
  __syncthreads();
  for (int idx = d; idx < TT * TT; idx += 64) {
    int tt = idx / TT, ss = idx % TT;
    float sc = 0.f;
#pragma unroll
    for (int k = 0; k < DOUT; k++) sc = fmaf(Qs[tt][k], Ks[ss][k], sc);
    at[tt][ss] = sc * 0.125f;
  }
  __syncthreads();
  if (d < TT) {
    float mx = -1e30f;
#pragma unroll
    for (int s = 0; s < TT; s++) mx = fmaxf(mx, at[d][s]);
    float sum = 0.f;
#pragma unroll
    for (int s = 0; s < TT; s++) { float e = __expf(at[d][s] - mx); at[d][s] = e; sum += e; }
    float inv = 1.f / sum;
#pragma unroll
    for (int s = 0; s < TT; s++) at[d][s] *= inv;
  }
  __syncthreads();
  float o[TT];
#pragma unroll
  for (int t = 0; t < TT; t++) o[t] = 0.f;
#pragma unroll
  for (int s = 0; s < TT; s++) {
    float vv = vr[s];
#pragma unroll
    for (int t = 0; t < TT; t++) o[t] = fmaf(at[t][s], vv, o[t]);
  }
#pragma unroll
  for (int t = 0; t < TT; t++)
    out[((size_t)(b * TT + t) * NN + n) * DOUT + d] = o[t];
}

__global__ __launch_bounds__(256) void k_hlast(const float* __restrict__ h, float* __restrict__ o) {
  int i = blockIdx.x * 256 + threadIdx.x;
  if (i < BB * NN * DOUT) o[i] = h[i];
}

extern "C" void kernel_launch(void* const* d_in, const int* in_sizes, int n_in,
                              void* d_out, int out_size, void* d_ws, size_t ws_size,
                              hipStream_t stream) {
  const float* x        = (const float*)d_in[0];
  const float* init_st  = (const float*)d_in[1];
  const float* ne_tod   = (const float*)d_in[2];
  const float* ne_dow   = (const float*)d_in[3];
  const float* E        = (const float*)d_in[4];
  const float* Wtod     = (const float*)d_in[5];
  const float* btod     = (const float*)d_in[6];
  const float* Wdow     = (const float*)d_in[7];
  const float* bdow     = (const float*)d_in[8];
  const float* WQ       = (const float*)d_in[9];
  const float* bQ       = (const float*)d_in[10];
  const float* WK       = (const float*)d_in[11];
  const float* bK       = (const float*)d_in[12];
  const float* WV       = (const float*)d_in[13];
  const float* bV       = (const float*)d_in[14];
  const float* Wpool_g  = (const float*)d_in[15];
  const float* bpool_g  = (const float*)d_in[16];
  const float* Wpool_c  = (const float*)d_in[17];
  const float* bpool_c  = (const float*)d_in[18];

  float* out = (float*)d_out;
  float* hlast_out = out + (size_t)BTN * DOUT;
  // park f16 seq history in the (not-yet-written) front of d_out: 25.2 MB < 50.3 MB
  f16* seqb = (f16*)d_out;

  char* P = (char*)d_ws;
  auto alloc = [&](size_t bytes) { char* r = P; P += (bytes + 255) & ~(size_t)255; return r; };
  f16* curh  = (f16*)alloc((size_t)BB * TT * DIN * NN * 2);   // 8.26 MB
  f16* curl  = (f16*)alloc((size_t)BB * TT * DIN * NN * 2);   // 8.26 MB
  float* Wg  = (float*)alloc((size_t)NN * KFP * 128 * 4);     // 92.3 MB
  float* Wc  = (float*)alloc((size_t)NN * KFP * 64 * 4);      // 46.1 MB
  float* bg  = (float*)alloc((size_t)NN * 128 * 4);
  float* bc  = (float*)alloc((size_t)NN * 64 * 4);
  float* hb  = (float*)alloc((size_t)BB * NN * DOUT * 4);     // 4.2 MB
  f16* wbt   = (f16*)alloc((size_t)3 * DOUT * DOUT * 2);
  float* biasb = (float*)alloc(192 * 4);
  float* rb  = (float*)alloc((size_t)BB * NN * DOUT * 4);     // 4.2 MB
  float* zhb = (float*)alloc((size_t)BB * NN * DOUT * 4);     // 4.2 MB
  char* LOOP = P;  // loop-scoped region, overlaid by qkvb after the loop
  f16* Ah    = (f16*)alloc((size_t)BB * NN * NN * 2);         // 33.6 MB
  f16* Al    = (f16*)alloc((size_t)BB * NN * NN * 2);         // 33.6 MB
  float* T1g = (float*)alloc((size_t)BB * NN * FP * 4);       // 6.3 MB
  float* T1c = (float*)alloc((size_t)BB * NN * DOUT * 4);     // 4.2 MB
  f16* qkvb  = (f16*)LOOP;  // 75.5 MB <= 77.7 MB loop region
  // total ws ~246 MB (< 260.6 MB proven in round 1)

  k_embedT<<<(BB * TT * DIN * NN + 255) / 256, 256, 0, stream>>>(x, Wtod, btod, Wdow, bdow, curh, curl);
  k_pool<<<dim3(KFP / 8, NN / 64), 256, 0, stream>>>(E, Wpool_g, Wg, 128);
  k_pool<<<dim3(KFP / 16, NN / 64), 256, 0, stream>>>(E, Wpool_c, Wc, 64);
  k_poolb<<<(NN * 128 + 255) / 256, 256, 0, stream>>>(E, bpool_g, bg, 128);
  k_poolb<<<(NN * 64 + 255) / 256, 256, 0, stream>>>(E, bpool_c, bc, 64);
  k_inith<<<(BB * NN * DOUT + 255) / 256, 256, 0, stream>>>(init_st, hb);
  k_cvtw<<<(3 * DOUT * DOUT + 192 + 255) / 256, 256, 0, stream>>>(WQ, WK, WV, bQ, bK, bV, wbt, biasb);

  for (int t = 0; t < TT; t++) {
    k_scores<<<dim3(NN / 4, BB), 256, 0, stream>>>(E, ne_tod, ne_dow, t, Ah, Al);
    k_spmv_g<<<dim3(NN / 32, BB), 256, 0, stream>>>(Ah, Al, curh, curl, t, hb, T1g);
    k_nodemm_g<<<NN, 256, 0, stream>>>(curh, curl, t, hb, T1g, Wg, bg, rb, zhb);
    k_spmv_c<<<dim3(NN / 32, BB), 256, 0, stream>>>(Ah, Al, zhb, T1c);
    k_nodemm_c<<<NN, 256, 0, stream>>>(curh, curl, t, hb, zhb, T1g, T1c, Wc, bc, rb, hb, seqb);
  }

  k_qkv<<<BTN / 128, 256, 0, stream>>>(seqb, wbt, biasb, qkvb);
  k_attn2<<<dim3(NN, BB), 64, 0, stream>>>(qkvb, out);
  k_hlast<<<(BB * NN * DOUT + 255) / 256, 256, 0, stream>>>(hb, hlast_out);
}